// Round 14
// baseline (132.267 us; speedup 1.0000x reference)
//
#include <hip/hip_runtime.h>
#include <stdint.h>

typedef unsigned short u16;
typedef float f32x4 __attribute__((ext_vector_type(4)));
typedef float f32x16 __attribute__((ext_vector_type(16)));
typedef __bf16 bf16x8 __attribute__((ext_vector_type(8)));

#define AS1 __attribute__((address_space(1)))
#define AS3 __attribute__((address_space(3)))

// 1/sqrt(Dh) * log2(e), folded into w_q/b_q so softmax works in exp2 domain
#define QK_SCALE 0.18033688011112042f

__device__ __forceinline__ u16 f32_to_bf16(float f) {
    unsigned u = __float_as_uint(f);
    unsigned r = u + 0x7fffu + ((u >> 16) & 1u);
    return (u16)(r >> 16);
}

__device__ __forceinline__ void gload_lds16(const u16* g, u16* l) {
    __builtin_amdgcn_global_load_lds((const AS1 unsigned int*)g,
                                     (AS3 unsigned int*)l, 16, 0, 0);
}

// element offset into a [rows][64]-u16 tile, XOR-swizzled at 16B-chunk granularity
__device__ __forceinline__ int swz(int row, int col8) {
    return row * 64 + (((col8 ^ (row & 7)) & 7) << 3);
}
// V-transpose swizzle: spreads the dh-column write collapse (dh>>3 folded in)
__device__ __forceinline__ int swzv(int row, int col8) {
    return row * 64 + (((col8 ^ row ^ (row >> 3)) & 7) << 3);
}

// ---------------- f32 -> bf16 convert (x | w_in | w_out in one launch) -----
__global__ __launch_bounds__(256) void cvt_bf16_3(const float4* __restrict__ in0,
                                                  const float4* __restrict__ in1,
                                                  const float4* __restrict__ in2,
                                                  uint2* __restrict__ out,
                                                  int n0, int n1, int ntot) {
    for (int i = blockIdx.x * blockDim.x + threadIdx.x; i < ntot;
         i += gridDim.x * blockDim.x) {
        float4 v;
        if (i < n0) v = in0[i];
        else if (i < n0 + n1) {
            v = in1[i - n0];
            if (((i - n0) >> 8) < 1024) {  // q-projection rows pre-scaled
                v.x *= QK_SCALE; v.y *= QK_SCALE; v.z *= QK_SCALE; v.w *= QK_SCALE;
            }
        } else v = in2[i - n0 - n1];
        uint2 o;
        o.x = (unsigned)f32_to_bf16(v.x) | ((unsigned)f32_to_bf16(v.y) << 16);
        o.y = (unsigned)f32_to_bf16(v.z) | ((unsigned)f32_to_bf16(v.w) << 16);
        out[i] = o;
    }
}

// ------- ring-4 deep-pipeline GEMM: C[M,N] = A[M,K] * B[N,K]^T + bias ------
template <int BNT, bool BF16_OUT>
__global__ __launch_bounds__(512, 2) void gemm_ring(const u16* __restrict__ A,
                                                    const u16* __restrict__ B,
                                                    const float* __restrict__ bias,
                                                    void* __restrict__ Cv,
                                                    int M, int N, int K,
                                                    int qcols, float qscale) {
    extern __shared__ u16 lds[];
    constexpr int NACC = BNT / 64;
    constexpr int NCH = (128 + BNT) >> 7;
    constexpr int ASZ = 128 * 32;
    constexpr int BSZ = BNT * 32;
    const int t = threadIdx.x;
    const int l = t & 63, w = t >> 6;
    const int lr = l & 15, lhi = l >> 4;
    const int wm = w >> 2, wn = w & 3;
    const int orig = blockIdx.y * gridDim.x + blockIdx.x;   // nwg == 256
    const int sid = (orig & 7) * 32 + (orig >> 3);
    const int bm = sid & 31, bn = sid >> 5;

    const u16* Ag = A + (size_t)bm * 128 * K;
    const u16* Bg = B + (size_t)bn * BNT * K;

    auto STAGE = [&](int kt, int slot) {
        u16* As = lds + slot * ASZ;
        u16* Bs = lds + 4 * ASZ + slot * BSZ;
        {
            int c = t, row = c >> 2, cp = c & 3;
            int gc = (cp ^ ((row >> 1) & 3)) << 3;
            gload_lds16(Ag + (size_t)row * K + kt * 32 + gc, As + c * 8);
        }
        #pragma unroll
        for (int i = 0; i < NCH - 1; ++i) {
            int c = i * 512 + t, row = c >> 2, cp = c & 3;
            int gc = (cp ^ ((row >> 1) & 3)) << 3;
            gload_lds16(Bg + (size_t)row * K + kt * 32 + gc, Bs + c * 8);
        }
    };

    f32x4 acc[4][NACC] = {};
    const int NT = K >> 5;          // 32
    STAGE(0, 0);
    STAGE(1, 1);
    STAGE(2, 2);

    const int ckey = (lr >> 1) & 3;

    for (int kt = 0; kt < NT; ++kt) {
        if (kt < NT - 2) {
            if constexpr (NCH == 4) asm volatile("s_waitcnt vmcnt(8)" ::: "memory");
            else                    asm volatile("s_waitcnt vmcnt(4)" ::: "memory");
        } else if (kt == NT - 2) {
            if constexpr (NCH == 4) asm volatile("s_waitcnt vmcnt(4)" ::: "memory");
            else                    asm volatile("s_waitcnt vmcnt(2)" ::: "memory");
        } else {
            asm volatile("s_waitcnt vmcnt(0)" ::: "memory");
        }
        __builtin_amdgcn_s_barrier();
        __builtin_amdgcn_sched_barrier(0);   // reads/stage must not hoist above

        if (kt + 3 < NT) STAGE(kt + 3, (kt + 3) & 3);

        const u16* As = lds + (kt & 3) * ASZ;
        const u16* Bs = lds + 4 * ASZ + (kt & 3) * BSZ;
        bf16x8 af[4], bfv[NACC];
        #pragma unroll
        for (int m = 0; m < 4; ++m) {
            int row = wm * 64 + m * 16 + lr;
            af[m] = *(const bf16x8*)(As + row * 32 + ((lhi ^ ckey) << 3));
        }
        #pragma unroll
        for (int n = 0; n < NACC; ++n) {
            int row = wn * (BNT / 4) + n * 16 + lr;
            bfv[n] = *(const bf16x8*)(Bs + row * 32 + ((lhi ^ ckey) << 3));
        }
        __builtin_amdgcn_s_setprio(1);
        #pragma unroll
        for (int m = 0; m < 4; ++m)
            #pragma unroll
            for (int n = 0; n < NACC; ++n)
                acc[m][n] = __builtin_amdgcn_mfma_f32_16x16x32_bf16(
                    af[m], bfv[n], acc[m][n], 0, 0, 0);
        __builtin_amdgcn_s_setprio(0);
    }

    const int row0 = bm * 128 + wm * 64 + lhi * 4;
    const int col0 = bn * BNT + wn * (BNT / 4) + lr;
    #pragma unroll
    for (int n = 0; n < NACC; ++n) {
        int col = col0 + n * 16;
        float bv = bias[col];
        if (col < qcols) bv *= qscale;
        #pragma unroll
        for (int m = 0; m < 4; ++m)
            #pragma unroll
            for (int r = 0; r < 4; ++r) {
                int row = row0 + m * 16 + r;
                float v = acc[m][n][r] + bv;
                if constexpr (BF16_OUT)
                    ((u16*)Cv)[(size_t)row * N + col] = f32_to_bf16(v);
                else
                    ((float*)Cv)[(size_t)row * N + col] = v;
            }
    }
}

// V-transpose write: thread owns rows (2g, 2g+1), cols cl*8..cl*8+7.
__device__ __forceinline__ void write_vt(u16* vt, uint4 a, uint4 b, int g, int cl) {
    unsigned aw[4] = {a.x, a.y, a.z, a.w};
    unsigned bw[4] = {b.x, b.y, b.z, b.w};
    #pragma unroll
    for (int j = 0; j < 8; ++j) {
        int dh = cl * 8 + j;
        unsigned sel = (j & 1) ? 0x07060302u : 0x05040100u;
        unsigned v = __builtin_amdgcn_perm(bw[j >> 1], aw[j >> 1], sel);
        *(unsigned*)(vt + swzv(dh, g >> 2) + (2 * g & 7)) = v;
    }
}

// ---------- causal flash attention: 32x32 MFMA, dual-parity 8-wave --------
// Per block: q-tile 128 rows (4 waves x 32 q), kv parity split (waves 0-3
// even tiles, 4-7 odd), in-LDS combine.  P never touches LDS: swapped QK^T
// puts P[q=lane&31][kv=crow(r,hi)]; cvt_pk + v_permlane32_swap_b32 build the
// PV B-fragment in registers (crow(r,hi) = (r&3)+8(r>>2)+4hi, verified C/D
// layout).  LDS 48K; grid 512 with (qt,15-qt)-paired XCD mapping.
__global__ __launch_bounds__(512, 4) void attn_kernel(const u16* __restrict__ qkv,
                                                      u16* __restrict__ out) {
    __shared__ u16 Ks[2][2][64 * 64];  // 32K [parity][dbuf]; epilogue: mlX/Oq
    __shared__ u16 Vt[2][64 * 64];     // 16K [parity], transposed [dh][kv]
    const int t = threadIdx.x;
    const int w = t >> 6, l = t & 63;
    const int l31 = l & 31, hi = l >> 5;
    const int par = w >> 2, wq = w & 3;
    const int tp = t & 255;
    // XCD-chunked mapping; CU pairs (qt, 15-qt) -> uniform 17 iters per CU
    const int x = blockIdx.x & 7, m = blockIdx.x >> 3;   // m 0..63 per XCD
    const int s5 = m >> 5, g = m & 31;
    const int qt = s5 ? (15 - (g & 15)) : (g & 15);
    const int bh = x * 4 + (g >> 4) + 2 * s5;
    const int h = bh & 15, b = bh >> 4;

    const u16* Kg = qkv + ((size_t)(b * 2048)) * 3072 + 1024 + h * 64;
    const u16* Vg = qkv + ((size_t)(b * 2048)) * 3072 + 2048 + h * 64;
    const int vg = tp >> 3, vcl = tp & 7;
    float2* mlX = (float2*)&Ks[0][0][0];   // epilogue-only alias
    u16* Oq = &Ks[1][0][0];                // epilogue-only alias (16K)

    // Q: lane owns q-row qt*128 + wq*32 + l31, k slices 16c+8hi..+7
    const int qmine = qt * 128 + wq * 32 + l31;
    const u16* Qrow = qkv + ((size_t)(b * 2048 + qmine)) * 3072 + h * 64;
    bf16x8 qv[4];
    #pragma unroll
    for (int c = 0; c < 4; ++c)
        qv[c] = *(const bf16x8*)(Qrow + 16 * c + 8 * hi);

    // prologue: stage K(par) -> Ks[par][0], V(par) -> Vt[par]
    #pragma unroll
    for (int i = 0; i < 2; ++i) {
        int c = i * 256 + tp, r = c >> 3, cl = c & 7;
        gload_lds16(Kg + ((size_t)(par * 64 + r)) * 3072 + ((cl ^ (r & 7)) << 3),
                    &Ks[par][0][c * 8]);
    }
    {
        uint4 va0 = *(const uint4*)(Vg + ((size_t)(par * 64 + 2 * vg)) * 3072 + vcl * 8);
        uint4 vb0 = *(const uint4*)(Vg + ((size_t)(par * 64 + 2 * vg + 1)) * 3072 + vcl * 8);
        write_vt(Vt[par], va0, vb0, vg, vcl);
    }
    __syncthreads();

    f32x16 acc0 = {}, acc1 = {};
    float m_run = -1e30f, l_run = 0.f;   // per-lane, q = l31 (dup across hi)
    int cur = 0;
    const int nt = qt + 1;

    for (int it = 0; it < nt; ++it) {
        const int t64 = 2 * it + par;
        const bool active = (t64 * 64 <= qt * 128 + wq * 32 + 31);
        const bool pf = (t64 + 2 <= 2 * qt + 1);
        uint4 va, vb;
        if (pf) {
            #pragma unroll
            for (int i = 0; i < 2; ++i) {
                int c = i * 256 + tp, r = c >> 3, cl = c & 7;
                gload_lds16(Kg + ((size_t)((t64 + 2) * 64 + r)) * 3072 +
                                ((cl ^ (r & 7)) << 3),
                            &Ks[par][cur ^ 1][c * 8]);
            }
            va = *(const uint4*)(Vg + ((size_t)((t64 + 2) * 64 + 2 * vg)) * 3072 + vcl * 8);
            vb = *(const uint4*)(Vg + ((size_t)((t64 + 2) * 64 + 2 * vg + 1)) * 3072 + vcl * 8);
        }

        if (active) {
            // S^T = K Q^T: s0 = kv 0-31, s1 = kv 32-63; col q = l31
            const u16* Kc = &Ks[par][cur][0];
            f32x16 s0, s1;
            __builtin_amdgcn_s_setprio(1);
            {
                f32x16 z16 = {};
                bf16x8 k0 = *(const bf16x8*)(Kc + swz(l31, hi));
                bf16x8 k1 = *(const bf16x8*)(Kc + swz(32 + l31, hi));
                s0 = __builtin_amdgcn_mfma_f32_32x32x16_bf16(k0, qv[0], z16, 0, 0, 0);
                s1 = __builtin_amdgcn_mfma_f32_32x32x16_bf16(k1, qv[0], z16, 0, 0, 0);
            }
            #pragma unroll
            for (int c = 1; c < 4; ++c) {
                bf16x8 k0 = *(const bf16x8*)(Kc + swz(l31, 2 * c + hi));
                bf16x8 k1 = *(const bf16x8*)(Kc + swz(32 + l31, 2 * c + hi));
                s0 = __builtin_amdgcn_mfma_f32_32x32x16_bf16(k0, qv[c], s0, 0, 0, 0);
                s1 = __builtin_amdgcn_mfma_f32_32x32x16_bf16(k1, qv[c], s1, 0, 0, 0);
            }
            __builtin_amdgcn_s_setprio(0);

            if (t64 >= 2 * qt) {  // causal mask (only last tiles are partial)
                #pragma unroll
                for (int r = 0; r < 16; ++r) {
                    int kv = t64 * 64 + (r & 3) + 8 * (r >> 2) + 4 * hi;
                    if (kv > qmine) s0[r] = -1e30f;
                    if (kv + 32 > qmine) s1[r] = -1e30f;
                }
            }
            // row max: in-thread tree over 32 + one cross-half shfl
            float tm[16];
            #pragma unroll
            for (int r = 0; r < 16; ++r) tm[r] = fmaxf(s0[r], s1[r]);
            #pragma unroll
            for (int off = 8; off >= 1; off >>= 1)
                #pragma unroll
                for (int i2 = 0; i2 < 8; ++i2)
                    if (i2 < off) tm[i2] = fmaxf(tm[i2], tm[i2 + off]);
            float mx = fmaxf(tm[0], __shfl_xor(tm[0], 32, 64));

            if (__any(mx > m_run + 8.f)) {  // defer-max (THR=8, exp2 domain)
                float mn = fmaxf(m_run, mx);
                float alpha = exp2f(m_run - mn);
                m_run = mn;
                l_run *= alpha;
                #pragma unroll
                for (int r = 0; r < 16; ++r) { acc0[r] *= alpha; acc1[r] *= alpha; }
            }

            float rs = 0.f;
            #pragma unroll
            for (int r = 0; r < 16; ++r) {
                float a0 = exp2f(s0[r] - m_run);
                float a1 = exp2f(s1[r] - m_run);
                s0[r] = a0; s1[r] = a1;
                rs += a0 + a1;
            }
            l_run += rs;

            // PV: in-register P frag via cvt_pk + permlane32_swap, then
            // acc[dh-tile] += mfma32(V^T frag, P frag)
            const u16* Vc = &Vt[par][0];
            __builtin_amdgcn_s_setprio(1);
#define PV_STEP(SV, CC)                                                          \
            {                                                                    \
                constexpr int base = 8 * ((CC) & 1);                             \
                union { unsigned u; __bf16 hh[2]; } p0a, p0b, p1a, p1b;          \
                p0a.hh[0] = (__bf16)SV[base + 0]; p0a.hh[1] = (__bf16)SV[base + 1]; \
                p0b.hh[0] = (__bf16)SV[base + 2]; p0b.hh[1] = (__bf16)SV[base + 3]; \
                p1a.hh[0] = (__bf16)SV[base + 4]; p1a.hh[1] = (__bf16)SV[base + 5]; \
                p1b.hh[0] = (__bf16)SV[base + 6]; p1b.hh[1] = (__bf16)SV[base + 7]; \
                unsigned w0 = p0a.u, w2 = p1a.u, w1 = p0b.u, w3 = p1b.u;         \
                asm volatile("v_permlane32_swap_b32 %0, %1" : "+v"(w0), "+v"(w2)); \
                asm volatile("v_permlane32_swap_b32 %0, %1" : "+v"(w1), "+v"(w3)); \
                union { uint4 u4; bf16x8 f; } pa;                                \
                pa.u4 = make_uint4(w0, w1, w2, w3);                              \
                bf16x8 av0 = *(const bf16x8*)(Vc + swzv(l31, 2 * (CC) + hi));    \
                bf16x8 av1 = *(const bf16x8*)(Vc + swzv(32 + l31, 2 * (CC) + hi)); \
                acc0 = __builtin_amdgcn_mfma_f32_32x32x16_bf16(av0, pa.f, acc0, 0, 0, 0); \
                acc1 = __builtin_amdgcn_mfma_f32_32x32x16_bf16(av1, pa.f, acc1, 0, 0, 0); \
            }
            PV_STEP(s0, 0)
            PV_STEP(s0, 1)
            PV_STEP(s1, 2)
            PV_STEP(s1, 3)
#undef PV_STEP
            __builtin_amdgcn_s_setprio(0);
        }

        __syncthreads();   // all reads of Vt[par]/Ks done
        if (pf) write_vt(Vt[par], va, vb, vg, vcl);
        __syncthreads();   // Vt ready; prefetched K drained
        cur ^= 1;
    }

    l_run += __shfl_xor(l_run, 32, 64);   // combine hi-halves' partial sums

    const int qloc = wq * 32 + l31;
    if (par == 1) {   // publish (m,l) + unnormalized O^T quads into Oq
        if (hi == 0) mlX[qloc] = make_float2(m_run, l_run);
#define PUB(ACC, TT)                                                             \
        _Pragma("unroll")                                                        \
        for (int a = 0; a < 4; ++a) {                                            \
            union { uint2 u2; u16 s4[4]; } o;                                    \
            o.s4[0] = f32_to_bf16(ACC[4 * a + 0]);                               \
            o.s4[1] = f32_to_bf16(ACC[4 * a + 1]);                               \
            o.s4[2] = f32_to_bf16(ACC[4 * a + 2]);                               \
            o.s4[3] = f32_to_bf16(ACC[4 * a + 3]);                               \
            *(uint2*)&Oq[qloc * 64 + (((4 * (TT) + a) ^ (qloc & 7)) << 3) + 4 * hi] = o.u2; \
        }
        PUB(acc0, 0)
        PUB(acc1, 1)
#undef PUB
    }
    __syncthreads();
    if (par == 0) {   // combine parities, write back into Oq
        float2 m1 = mlX[qloc];
        float mm = fmaxf(m_run, m1.x);
        float e0 = exp2f(m_run - mm), e1 = exp2f(m1.x - mm);
        float inv = 1.0f / (l_run * e0 + m1.y * e1);
        float c0 = e0 * inv, c1 = e1 * inv;
#define CMB(ACC, TT)                                                             \
        _Pragma("unroll")                                                        \
        for (int a = 0; a < 4; ++a) {                                            \
            int ad = qloc * 64 + (((4 * (TT) + a) ^ (qloc & 7)) << 3) + 4 * hi;  \
            uint2 v1 = *(uint2*)&Oq[ad];                                         \
            __bf16* h4 = (__bf16*)&v1;                                           \
            union { uint2 u2; u16 s4[4]; } o;                                    \
            o.s4[0] = f32_to_bf16(ACC[4 * a + 0] * c0 + (float)h4[0] * c1);      \
            o.s4[1] = f32_to_bf16(ACC[4 * a + 1] * c0 + (float)h4[1] * c1);      \
            o.s4[2] = f32_to_bf16(ACC[4 * a + 2] * c0 + (float)h4[2] * c1);      \
            o.s4[3] = f32_to_bf16(ACC[4 * a + 3] * c0 + (float)h4[3] * c1);      \
            *(uint2*)&Oq[ad] = o.u2;                                             \
        }
        CMB(acc0, 0)
        CMB(acc1, 1)
#undef CMB
    }
    __syncthreads();
    // coalesced final store: 128 rows x 64 dh bf16 (unswizzle per 16B chunk)
    #pragma unroll
    for (int i = 0; i < 2; ++i) {
        int cch = i * 512 + t;
        int row = cch >> 3, ch = cch & 7;
        uint4 v = *(const uint4*)&Oq[row * 64 + ((ch ^ (row & 7)) << 3)];
        *(uint4*)&out[((size_t)(b * 2048 + qt * 128 + row)) * 1024 + h * 64 + ch * 8] = v;
    }
}

extern "C" void kernel_launch(void* const* d_in, const int* in_sizes, int n_in,
                              void* d_out, int out_size, void* d_ws, size_t ws_size,
                              hipStream_t stream) {
    const float* x = (const float*)d_in[0];
    const float* w_in = (const float*)d_in[1];
    const float* b_in = (const float*)d_in[2];
    const float* w_out = (const float*)d_in[3];
    const float* b_out = (const float*)d_in[4];
    float* out = (float*)d_out;

    // workspace layout (bf16), 48 MB
    u16* xb = (u16*)d_ws;                            // [4096][1024]
    u16* wib = xb + (size_t)4096 * 1024;             // [3072][1024]
    u16* wob = wib + (size_t)3072 * 1024;            // [1024][1024]
    u16* qkvb = wob + (size_t)1024 * 1024;           // [4096][3072]
    u16* attnb = qkvb + (size_t)4096 * 3072;         // [4096][1024]

    const int n0 = 4096 * 1024 / 4, n1 = 3072 * 1024 / 4, n2 = 1024 * 1024 / 4;
    cvt_bf16_3<<<2048, 256, 0, stream>>>((const float4*)x, (const float4*)w_in,
                                         (const float4*)w_out, (uint2*)xb,
                                         n0, n1, n0 + n1 + n2);

    (void)hipFuncSetAttribute((const void*)gemm_ring<384, true>,
                              hipFuncAttributeMaxDynamicSharedMemorySize, 131072);
    (void)hipFuncSetAttribute((const void*)gemm_ring<128, false>,
                              hipFuncAttributeMaxDynamicSharedMemorySize, 65536);

    // qkv = x @ w_in^T + b_in (q-part pre-scaled) -> bf16 [4096][3072]
    gemm_ring<384, true><<<dim3(32, 8), 512, 131072, stream>>>(
        xb, wib, b_in, qkvb, 4096, 3072, 1024, 1024, QK_SCALE);
    // causal flash attention (32x32 MFMA, in-register P, dual-parity)
    attn_kernel<<<512, 512, 0, stream>>>(qkvb, attnb);
    // out = attn @ w_out^T + b_out -> f32
    gemm_ring<128, false><<<dim3(32, 8), 512, 65536, stream>>>(
        attnb, wob, b_out, out, 4096, 1024, 1024, 0, 1.0f);
}

// Round 15
// 103.630 us; speedup vs baseline: 1.2763x; 1.2763x over previous
//
#include <hip/hip_runtime.h>
#include <stdint.h>

typedef unsigned short u16;
typedef float f32x4 __attribute__((ext_vector_type(4)));
typedef __bf16 bf16x8 __attribute__((ext_vector_type(8)));

#define AS1 __attribute__((address_space(1)))
#define AS3 __attribute__((address_space(3)))

// 1/sqrt(Dh) * log2(e), folded into w_q/b_q so softmax works in exp2 domain
#define QK_SCALE 0.18033688011112042f

__device__ __forceinline__ u16 f32_to_bf16(float f) {
    unsigned u = __float_as_uint(f);
    unsigned r = u + 0x7fffu + ((u >> 16) & 1u);
    return (u16)(r >> 16);
}

__device__ __forceinline__ float bf16_f(u16 u) {
    return __uint_as_float(((unsigned)u) << 16);
}

__device__ __forceinline__ void gload_lds16(const u16* g, u16* l) {
    __builtin_amdgcn_global_load_lds((const AS1 unsigned int*)g,
                                     (AS3 unsigned int*)l, 16, 0, 0);
}

// element offset into a [rows][64]-u16 tile, XOR-swizzled at 16B-chunk granularity
__device__ __forceinline__ int swz(int row, int col8) {
    return row * 64 + (((col8 ^ (row & 7)) & 7) << 3);
}
// V-transpose swizzle: spreads the dh-column write collapse (dh>>3 folded in)
__device__ __forceinline__ int swzv(int row, int col8) {
    return row * 64 + (((col8 ^ row ^ (row >> 3)) & 7) << 3);
}

// ---------------- f32 -> bf16 convert (x | w_in | w_out in one launch) -----
__global__ __launch_bounds__(256) void cvt_bf16_3(const float4* __restrict__ in0,
                                                  const float4* __restrict__ in1,
                                                  const float4* __restrict__ in2,
                                                  uint2* __restrict__ out,
                                                  int n0, int n1, int ntot) {
    for (int i = blockIdx.x * blockDim.x + threadIdx.x; i < ntot;
         i += gridDim.x * blockDim.x) {
        float4 v;
        if (i < n0) v = in0[i];
        else if (i < n0 + n1) {
            v = in1[i - n0];
            if (((i - n0) >> 8) < 1024) {  // q-projection rows pre-scaled
                v.x *= QK_SCALE; v.y *= QK_SCALE; v.z *= QK_SCALE; v.w *= QK_SCALE;
            }
        } else v = in2[i - n0 - n1];
        uint2 o;
        o.x = (unsigned)f32_to_bf16(v.x) | ((unsigned)f32_to_bf16(v.y) << 16);
        o.y = (unsigned)f32_to_bf16(v.z) | ((unsigned)f32_to_bf16(v.w) << 16);
        out[i] = o;
    }
}

// ------- ring-4 deep-pipeline GEMM: C[M,N] = A[M,K] * B[N,K]^T + bias ------
// BM=128, BN=BNT (384 or 128), BK=32, 8 waves (2Mx4N), per-wave 64 x BNT/4.
// Schedule/phase: vmcnt(2*NCH) -> s_barrier -> sched_barrier -> stage kt+3 ->
// ds_reads -> MFMA cluster (compiler-scheduled counted lgkm waits).
// XCD map: each XCD owns an 8bm x 4bn 2D tile (A-panel 2MB + B-panel 3MB
// L2-resident, vs 1D map's full-A 8MB re-stream per XCD).
template <int BNT, bool BF16_OUT>
__global__ __launch_bounds__(512, 2) void gemm_ring(const u16* __restrict__ A,
                                                    const u16* __restrict__ B,
                                                    const float* __restrict__ bias,
                                                    void* __restrict__ Cv,
                                                    int M, int N, int K,
                                                    int qcols, float qscale) {
    extern __shared__ u16 lds[];
    constexpr int NACC = BNT / 64;
    constexpr int NCH = (128 + BNT) >> 7;
    constexpr int ASZ = 128 * 32;
    constexpr int BSZ = BNT * 32;
    const int t = threadIdx.x;
    const int l = t & 63, w = t >> 6;
    const int lr = l & 15, lhi = l >> 4;
    const int wm = w >> 2, wn = w & 3;
    const int orig = blockIdx.y * gridDim.x + blockIdx.x;   // nwg == 256
    const int x = orig & 7, lo = orig >> 3;                 // XCD, local 0..31
    const int bm = (x & 3) * 8 + (lo & 7);                  // 8 bm per XCD
    const int bn = (x >> 2) * 4 + (lo >> 3);                // 4 bn per XCD

    const u16* Ag = A + (size_t)bm * 128 * K;
    const u16* Bg = B + (size_t)bn * BNT * K;

    auto STAGE = [&](int kt, int slot) {
        u16* As = lds + slot * ASZ;
        u16* Bs = lds + 4 * ASZ + slot * BSZ;
        {
            int c = t, row = c >> 2, cp = c & 3;
            int gc = (cp ^ ((row >> 1) & 3)) << 3;
            gload_lds16(Ag + (size_t)row * K + kt * 32 + gc, As + c * 8);
        }
        #pragma unroll
        for (int i = 0; i < NCH - 1; ++i) {
            int c = i * 512 + t, row = c >> 2, cp = c & 3;
            int gc = (cp ^ ((row >> 1) & 3)) << 3;
            gload_lds16(Bg + (size_t)row * K + kt * 32 + gc, Bs + c * 8);
        }
    };

    f32x4 acc[4][NACC] = {};
    const int NT = K >> 5;          // 32
    STAGE(0, 0);
    STAGE(1, 1);
    STAGE(2, 2);

    const int ckey = (lr >> 1) & 3;

    for (int kt = 0; kt < NT; ++kt) {
        if (kt < NT - 2) {
            if constexpr (NCH == 4) asm volatile("s_waitcnt vmcnt(8)" ::: "memory");
            else                    asm volatile("s_waitcnt vmcnt(4)" ::: "memory");
        } else if (kt == NT - 2) {
            if constexpr (NCH == 4) asm volatile("s_waitcnt vmcnt(4)" ::: "memory");
            else                    asm volatile("s_waitcnt vmcnt(2)" ::: "memory");
        } else {
            asm volatile("s_waitcnt vmcnt(0)" ::: "memory");
        }
        __builtin_amdgcn_s_barrier();
        __builtin_amdgcn_sched_barrier(0);   // reads/stage must not hoist above

        if (kt + 3 < NT) STAGE(kt + 3, (kt + 3) & 3);

        const u16* As = lds + (kt & 3) * ASZ;
        const u16* Bs = lds + 4 * ASZ + (kt & 3) * BSZ;
        bf16x8 af[4], bfv[NACC];
        #pragma unroll
        for (int m = 0; m < 4; ++m) {
            int row = wm * 64 + m * 16 + lr;
            af[m] = *(const bf16x8*)(As + row * 32 + ((lhi ^ ckey) << 3));
        }
        #pragma unroll
        for (int n = 0; n < NACC; ++n) {
            int row = wn * (BNT / 4) + n * 16 + lr;
            bfv[n] = *(const bf16x8*)(Bs + row * 32 + ((lhi ^ ckey) << 3));
        }
        __builtin_amdgcn_s_setprio(1);
        #pragma unroll
        for (int m = 0; m < 4; ++m)
            #pragma unroll
            for (int n = 0; n < NACC; ++n)
                acc[m][n] = __builtin_amdgcn_mfma_f32_16x16x32_bf16(
                    af[m], bfv[n], acc[m][n], 0, 0, 0);
        __builtin_amdgcn_s_setprio(0);
    }

    const int row0 = bm * 128 + wm * 64 + lhi * 4;
    const int col0 = bn * BNT + wn * (BNT / 4) + lr;
    #pragma unroll
    for (int n = 0; n < NACC; ++n) {
        int col = col0 + n * 16;
        float bv = bias[col];
        if (col < qcols) bv *= qscale;
        #pragma unroll
        for (int m = 0; m < 4; ++m)
            #pragma unroll
            for (int r = 0; r < 4; ++r) {
                int row = row0 + m * 16 + r;
                float v = acc[m][n][r] + bv;
                if constexpr (BF16_OUT)
                    ((u16*)Cv)[(size_t)row * N + col] = f32_to_bf16(v);
                else
                    ((float*)Cv)[(size_t)row * N + col] = v;
            }
    }
}

// V-transpose write: thread owns rows (2g, 2g+1), cols cl*8..cl*8+7.
// v_perm packs the two 16-bit halves in one op per output word.
__device__ __forceinline__ void write_vt(u16* vt, uint4 a, uint4 b, int g, int cl) {
    unsigned aw[4] = {a.x, a.y, a.z, a.w};
    unsigned bw[4] = {b.x, b.y, b.z, b.w};
    #pragma unroll
    for (int j = 0; j < 8; ++j) {
        int dh = cl * 8 + j;
        unsigned sel = (j & 1) ? 0x07060302u : 0x05040100u;
        unsigned v = __builtin_amdgcn_perm(bw[j >> 1], aw[j >> 1], sel);
        *(unsigned*)(vt + swzv(dh, g >> 2) + (2 * g & 7)) = v;
    }
}

// ---------------- causal flash attention: dual-parity 8-wave blocks --------
// Measured-best structure (52.9 us): static 64KB LDS, Vt single-buffered per
// parity, two barriers per KV iter, K dbuf via global_load_lds.  VGPR 64,
// no spill.  Levers closed by measurement: more waves (R12 spill), dual-frag
// (R9/R10), mfma32 (R14), counted-vmcnt (R8 neutral) — do not revisit.
__global__ __launch_bounds__(512, 4) void attn_kernel(const u16* __restrict__ qkv,
                                                      u16* __restrict__ out) {
    __shared__ u16 Ks[2][2][64 * 64];  // [parity][dbuf], swz layout
    __shared__ u16 Vt[2][64 * 64];     // [parity], transposed [dh][kv], swzv
    __shared__ u16 Ps[8][16 * 64];     // per-wave P scratch / par1 O-tile
    const int t = threadIdx.x;
    const int w = t >> 6, l = t & 63;
    const int lr = l & 15, lhi = l >> 4;
    const int par = w >> 2, wl = w & 3;
    const int tp = t & 255;            // index within parity's 4 waves
    const int orig = blockIdx.x;
    const int sid = (orig & 7) * 64 + (orig >> 3);   // XCD-chunked
    const int bh = sid >> 4, bi = sid & 15;
    const int h = bh & 15, b = bh >> 4;

    const u16* Kg = qkv + ((size_t)(b * 2048)) * 3072 + 1024 + h * 64;
    const u16* Vg = qkv + ((size_t)(b * 2048)) * 3072 + 2048 + h * 64;
    const int vg = tp >> 3, vcl = tp & 7;
    u16* Pw = Ps[w];
    unsigned* Pst = (unsigned*)Pw;
    float2* mlX = (float2*)&Ks[0][0][0];

    #pragma unroll 1
    for (int pass = 0; pass < 2; ++pass) {
        const int qt = pass ? (31 - bi) : bi;
        __syncthreads();  // previous pass's LDS reads complete

        const u16* Qrow = qkv + ((size_t)(b * 2048 + qt * 64 + wl * 16 + lr)) * 3072 + h * 64;
        bf16x8 qf0 = *(const bf16x8*)(Qrow + lhi * 8);
        bf16x8 qf1 = *(const bf16x8*)(Qrow + 32 + lhi * 8);

        uint4 va = {0, 0, 0, 0}, vbr = {0, 0, 0, 0};
        if (par <= qt) {
            #pragma unroll
            for (int i = 0; i < 2; ++i) {
                int c = i * 256 + tp, r = c >> 3, cl = c & 7;
                gload_lds16(Kg + ((size_t)(par * 64 + r)) * 3072 + ((cl ^ (r & 7)) << 3),
                            &Ks[par][0][c * 8]);
            }
            va = *(const uint4*)(Vg + ((size_t)(par * 64 + 2 * vg)) * 3072 + vcl * 8);
            vbr = *(const uint4*)(Vg + ((size_t)(par * 64 + 2 * vg + 1)) * 3072 + vcl * 8);
            write_vt(Vt[par], va, vbr, vg, vcl);
        }
        __syncthreads();

        f32x4 acc[4] = {};
        float m_run = -1e30f, l_run = 0.f;
        int cur = 0;
        const int nt = (qt >> 1) + 1;

        for (int it = 0; it < nt; ++it) {
            const int t64 = 2 * it + par;
            const bool active = (t64 <= qt);
            const bool pfv = (t64 + 2 <= qt);
            if (pfv) {
                #pragma unroll
                for (int i = 0; i < 2; ++i) {
                    int c = i * 256 + tp, r = c >> 3, cl = c & 7;
                    gload_lds16(Kg + ((size_t)((t64 + 2) * 64 + r)) * 3072 +
                                    ((cl ^ (r & 7)) << 3),
                                &Ks[par][cur ^ 1][c * 8]);
                }
                va = *(const uint4*)(Vg + ((size_t)((t64 + 2) * 64 + 2 * vg)) * 3072 + vcl * 8);
                vbr = *(const uint4*)(Vg + ((size_t)((t64 + 2) * 64 + 2 * vg + 1)) * 3072 + vcl * 8);
            }

            if (active) {
                f32x4 sv[4] = {};
                __builtin_amdgcn_s_setprio(1);
                #pragma unroll
                for (int kks = 0; kks < 2; ++kks) {
                    #pragma unroll
                    for (int n = 0; n < 4; ++n) {
                        bf16x8 kf = *(const bf16x8*)(&Ks[par][cur][swz(n * 16 + lr, kks * 4 + lhi)]);
                        sv[n] = __builtin_amdgcn_mfma_f32_16x16x32_bf16(
                            kf, kks ? qf1 : qf0, sv[n], 0, 0, 0);
                    }
                }
                __builtin_amdgcn_s_setprio(0);

                if (t64 == qt) {
                    #pragma unroll
                    for (int n = 0; n < 4; ++n)
                        #pragma unroll
                        for (int r = 0; r < 4; ++r)
                            if ((n * 16 + lhi * 4 + r) > (wl * 16 + lr)) sv[n][r] = -1e30f;
                }
                float t0 = fmaxf(fmaxf(sv[0][0], sv[0][1]), fmaxf(sv[0][2], sv[0][3]));
                float t1 = fmaxf(fmaxf(sv[1][0], sv[1][1]), fmaxf(sv[1][2], sv[1][3]));
                float t2 = fmaxf(fmaxf(sv[2][0], sv[2][1]), fmaxf(sv[2][2], sv[2][3]));
                float t3 = fmaxf(fmaxf(sv[3][0], sv[3][1]), fmaxf(sv[3][2], sv[3][3]));
                float mx = fmaxf(fmaxf(t0, t1), fmaxf(t2, t3));
                mx = fmaxf(mx, __shfl_xor(mx, 16, 64));
                mx = fmaxf(mx, __shfl_xor(mx, 32, 64));

                if (__any(mx > m_run + 8.f)) {
                    float mn = fmaxf(m_run, mx);
                    float alpha = exp2f(m_run - mn);
                    m_run = mn;
                    l_run *= alpha;
                    #pragma unroll
                    for (int r = 0; r < 4; ++r) {
                        float ar = __shfl(alpha, lhi * 4 + r, 16);
                        #pragma unroll
                        for (int n = 0; n < 4; ++n) acc[n][r] *= ar;
                    }
                }

                float rs = 0.f;
                #pragma unroll
                for (int n = 0; n < 4; ++n)
                    #pragma unroll
                    for (int r = 0; r < 4; ++r) {
                        float pe = exp2f(sv[n][r] - m_run);
                        sv[n][r] = pe;
                        rs += pe;
                    }
                l_run += rs;

                // pack 4 kv-adjacent bf16 -> uint2, single b64 store per n
                #pragma unroll
                for (int n = 0; n < 4; ++n) {
                    union { uint2 u2; __bf16 hh[4]; } pk;
                    pk.hh[0] = (__bf16)sv[n][0];
                    pk.hh[1] = (__bf16)sv[n][1];
                    pk.hh[2] = (__bf16)sv[n][2];
                    pk.hh[3] = (__bf16)sv[n][3];
                    int pp = 8 * n + 2 * lhi;
                    *(uint2*)&Pst[lr * 32 + (((pp >> 2) ^ (lr & 7)) << 2) + (pp & 3)] = pk.u2;
                }

                __builtin_amdgcn_s_setprio(1);
                #pragma unroll
                for (int kks = 0; kks < 2; ++kks) {
                    bf16x8 pa = *(const bf16x8*)(Pw + lr * 64 +
                                                 (((kks * 4 + lhi) ^ (lr & 7)) << 3));
                    #pragma unroll
                    for (int n = 0; n < 4; ++n) {
                        bf16x8 vb = *(const bf16x8*)(&Vt[par][swzv(n * 16 + lr, kks * 4 + lhi)]);
                        acc[n] = __builtin_amdgcn_mfma_f32_16x16x32_bf16(pa, vb, acc[n], 0, 0, 0);
                    }
                }
                __builtin_amdgcn_s_setprio(0);
            }

            __syncthreads();   // all PV reads of Vt[par] done
            if (pfv) write_vt(Vt[par], va, vbr, vg, vcl);
            __syncthreads();   // Vt ready; prefetched K drained
            cur ^= 1;
        }

        l_run += __shfl_xor(l_run, 16, 64);
        l_run += __shfl_xor(l_run, 32, 64);

        if (par == 1) {
            if (lhi == 0) mlX[wl * 16 + lr] = make_float2(m_run, l_run);
            #pragma unroll
            for (int r = 0; r < 4; ++r)
                #pragma unroll
                for (int n = 0; n < 4; ++n)
                    Pw[(lhi * 4 + r) * 64 + n * 16 + lr] = f32_to_bf16(acc[n][r]);
        }
        __syncthreads();
        if (par == 0) {
            float2 m1l1 = mlX[wl * 16 + lr];
            float m = fmaxf(m_run, m1l1.x);
            float e0 = exp2f(m_run - m), e1 = exp2f(m1l1.x - m);
            float inv = 1.0f / (l_run * e0 + m1l1.y * e1);
            float c0 = e0 * inv, c1 = e1 * inv;
            const u16* Pq = Ps[4 + wl];
            #pragma unroll
            for (int r = 0; r < 4; ++r) {
                float c0r = __shfl(c0, lhi * 4 + r, 16);
                float c1r = __shfl(c1, lhi * 4 + r, 16);
                int qg = qt * 64 + wl * 16 + lhi * 4 + r;
                size_t base = ((size_t)(b * 2048 + qg)) * 1024 + h * 64;
                #pragma unroll
                for (int n = 0; n < 4; ++n) {
                    float v1 = bf16_f(Pq[(lhi * 4 + r) * 64 + n * 16 + lr]);
                    out[base + n * 16 + lr] = f32_to_bf16(acc[n][r] * c0r + v1 * c1r);
                }
            }
        }
    }
}

extern "C" void kernel_launch(void* const* d_in, const int* in_sizes, int n_in,
                              void* d_out, int out_size, void* d_ws, size_t ws_size,
                              hipStream_t stream) {
    const float* x = (const float*)d_in[0];
    const float* w_in = (const float*)d_in[1];
    const float* b_in = (const float*)d_in[2];
    const float* w_out = (const float*)d_in[3];
    const float* b_out = (const float*)d_in[4];
    float* out = (float*)d_out;

    // workspace layout (bf16), 48 MB
    u16* xb = (u16*)d_ws;                            // [4096][1024]
    u16* wib = xb + (size_t)4096 * 1024;             // [3072][1024]
    u16* wob = wib + (size_t)3072 * 1024;            // [1024][1024]
    u16* qkvb = wob + (size_t)1024 * 1024;           // [4096][3072]
    u16* attnb = qkvb + (size_t)4096 * 3072;         // [4096][1024]

    const int n0 = 4096 * 1024 / 4, n1 = 3072 * 1024 / 4, n2 = 1024 * 1024 / 4;
    cvt_bf16_3<<<2048, 256, 0, stream>>>((const float4*)x, (const float4*)w_in,
                                         (const float4*)w_out, (uint2*)xb,
                                         n0, n1, n0 + n1 + n2);

    (void)hipFuncSetAttribute((const void*)gemm_ring<384, true>,
                              hipFuncAttributeMaxDynamicSharedMemorySize, 131072);
    (void)hipFuncSetAttribute((const void*)gemm_ring<128, false>,
                              hipFuncAttributeMaxDynamicSharedMemorySize, 65536);

    // qkv = x @ w_in^T + b_in (q-part pre-scaled) -> bf16 [4096][3072]
    gemm_ring<384, true><<<dim3(32, 8), 512, 131072, stream>>>(
        xb, wib, b_in, qkvb, 4096, 3072, 1024, 1024, QK_SCALE);
    // causal flash attention (dual-parity, static 64KB — measured best)
    attn_kernel<<<512, 512, 0, stream>>>(qkvb, attnb);
    // out = attn @ w_out^T + b_out -> f32
    gemm_ring<128, false><<<dim3(32, 8), 512, 65536, stream>>>(
        attnb, wob, b_out, out, 4096, 1024, 1024, 0, 1.0f);
}